// Round 13
// baseline (587.598 us; speedup 1.0000x reference)
//
#include <hip/hip_runtime.h>
#include <hip/hip_cooperative_groups.h>

// SimplePoseGNN on MI355X — round 13.
// fp32 in/out; internal bf16 + fp32 accumulation; bf16 MFMA GEMMs.
// ALL graph/weight prep collapsed into ONE cooperative kernel (k_gprep, 544x256,
// grid.sync between phases): zero+tables -> deg -> block scan -> bsum scan ->
// finalize/norms -> CSR fill -> rowstats. 4 launches total.
// conv1 (r10): cooperative y-build w/ scalar tables, swizzled tileY, GEMM2 + Wout
// residual tile, channel-permuted 8B stores. k_gconv (r10): half-wave per row,
// params in VGPRs. k_head: 64-thread blocks. Graph mean via binary search.

namespace cg = cooperative_groups;

#define NN 139264
#define EE 278528
#define GG 8192
#define NBLK 544    // NN/256

typedef float f32x4 __attribute__((ext_vector_type(4)));
typedef __bf16 bf16x8 __attribute__((ext_vector_type(8)));
typedef unsigned short u16x8 __attribute__((ext_vector_type(8)));
typedef unsigned short u16x4 __attribute__((ext_vector_type(4)));

__device__ __forceinline__ float bf2f(unsigned short u) {
    unsigned int i = ((unsigned int)u) << 16;
    float f;
    __builtin_memcpy(&f, &i, 4);
    return f;
}
__device__ __forceinline__ unsigned short f2bf(float f) {
    unsigned int i;
    __builtin_memcpy(&i, &f, 4);
    i += 0x7fffu + ((i >> 16) & 1u);   // round-to-nearest-even
    return (unsigned short)(i >> 16);
}
__device__ __forceinline__ unsigned short bfbits(float f) {
    __bf16 b = (__bf16)f;
    return __builtin_bit_cast(unsigned short, b);
}

// ---------------- workspace layout (bytes) ----------------
#define OFF_DEG_OUT ((size_t)0)
#define OFF_DEG_IN  ((size_t)557056)
#define OFF_T       ((size_t)1114112)
#define OFF_NOUT    ((size_t)2785280)
#define OFF_NIN     ((size_t)3342336)
#define OFF_ROWPTR  ((size_t)3899392)
#define OFF_CURSOR  ((size_t)4460544)
#define OFF_CSRS    ((size_t)5017600)
#define OFF_WT2     ((size_t)6131712)
#define OFF_WTA     ((size_t)6262784)
#define OFF_WTB     ((size_t)6393856)
#define OFF_WTCLS   ((size_t)6524928)
#define OFF_WOT     ((size_t)6557696)
#define OFF_BNS     ((size_t)6565888)
#define OFF_BNH     ((size_t)6572032)
#define OFF_TAB     ((size_t)6578176)
#define OFF_PP      ((size_t)6587392)
#define OFF_BSUM    ((size_t)6595584)
#define OFF_R3      ((size_t)6599680)
#define OFF_H1W     ((size_t)8270848)
// total ~79.6 MB

// ---------------- one cooperative prep kernel ----------------
// phases: Z(zero deg + all tables) | deg atomics | block scan | bsum scan |
//         finalize+norms | CSR fill | rowstats.   grid.sync() between phases.
__launch_bounds__(256)
__global__ void k_gprep(const int* __restrict__ src, const int* __restrict__ dst,
                        const float* __restrict__ nf,
                        int* __restrict__ deg_out, int* __restrict__ deg_in,
                        int* __restrict__ rp, int* __restrict__ cursor, int* __restrict__ csr,
                        float* __restrict__ n_out, float* __restrict__ n_in,
                        int* __restrict__ bsum, float* __restrict__ T,
                        const float* __restrict__ Wc2, const float* __restrict__ Wb3a,
                        const float* __restrict__ Wb3b,
                        unsigned short* __restrict__ wt2, unsigned short* __restrict__ wta,
                        unsigned short* __restrict__ wtb,
                        const float* __restrict__ wcls, unsigned short* __restrict__ tcls,
                        const float* __restrict__ bng, const float* __restrict__ bnb,
                        const float* __restrict__ bnm, const float* __restrict__ bnv,
                        float* __restrict__ bns, float* __restrict__ bnh,
                        const float* __restrict__ Wout, unsigned short* __restrict__ wot,
                        const float* __restrict__ Wemb, const float* __restrict__ bemb,
                        const float* __restrict__ Wc1, const float* __restrict__ bc1,
                        const float* __restrict__ bc2,
                        float* __restrict__ TAB, float* __restrict__ PP) {
    cg::grid_group grid = cg::this_grid();
    __shared__ int sh[256];
    __shared__ int shS[NBLK];
    __shared__ int shT[256];
    int tid = threadIdx.x;
    int gtid = blockIdx.x * 256 + tid;   // 0..NN-1 (544*256 == NN)

    // ---- phase Z: zero degrees + all independent table prep
    deg_out[gtid] = 0;
    deg_in[gtid] = 0;
    if (gtid < 65536) {
        int k = gtid >> 8, n = gtid & 255;
        wt2[n * 256 + k] = f2bf(Wc2[gtid]);
        wta[n * 256 + k] = f2bf(Wb3a[gtid]);
        wtb[n * 256 + k] = f2bf(Wb3b[gtid]);
    }
    if (gtid < 16384) {
        int n = gtid >> 8, k = gtid & 255;
        tcls[gtid] = (n < 60) ? f2bf(wcls[k * 60 + n]) : (unsigned short)0;
    }
    if (gtid < 1536) {
        float inv = rsqrtf(bnv[gtid] + 1e-5f);
        float s = bng[gtid] * inv;
        bns[gtid] = s;
        bnh[gtid] = bnb[gtid] - bnm[gtid] * s;
    }
    if (gtid < 4096) {
        int n = gtid >> 8, k = gtid & 255;
        wot[gtid] = (n < 3) ? f2bf(Wout[k * 3 + n]) : (unsigned short)0;
    }
    if (gtid >= 131072 && gtid < 131328) {         // TAB (block 512)
        int c = gtid - 131072;
        float inv0 = rsqrtf(bnv[c] + 1e-5f);
        float s0 = bng[c] * inv0;
        float h0 = bnb[c] - bnm[c] * s0;
        float e0 = 0.f, e1 = 0.f, e2 = 0.f;
        for (int k = 0; k < 256; k++) {
            float w = Wc1[k * 256 + c];
            e0 = fmaf(Wemb[k], w, e0);
            e1 = fmaf(Wemb[256 + k], w, e1);
            e2 = fmaf(bemb[k], w, e2);
        }
        TAB[c]        = e0 * s0;
        TAB[256 + c]  = e1 * s0;
        TAB[512 + c]  = e2 * s0;
        TAB[768 + c]  = fmaf(bc1[c], s0, h0);
        float inv1 = rsqrtf(bnv[256 + c] + 1e-5f);
        float s1 = bng[256 + c] * inv1;
        TAB[1024 + c] = s1;
        TAB[1280 + c] = bnb[256 + c] - bnm[256 + c] * s1;
        TAB[1536 + c] = Wemb[c];
        TAB[1792 + c] = Wemb[256 + c];
        TAB[2048 + c] = bemb[c];
    }
    if (gtid >= 131328 && gtid < 131584) {         // PP (block 513)
        int cp = gtid - 131328;
        int w = cp >> 6, rs = (cp >> 2) & 15, nt = cp & 3;
        int c = w * 64 + nt * 16 + rs;
        PP[cp] = bc2[c];
        float inv2 = rsqrtf(bnv[512 + c] + 1e-5f);
        float s2 = bng[512 + c] * inv2;
        PP[256 + cp] = s2;
        PP[512 + cp] = bnb[512 + c] - bnm[512 + c] * s2;
        float inv3 = rsqrtf(bnv[768 + c] + 1e-5f);
        float s3 = bng[768 + c] * inv3;
        PP[768 + cp] = s3;
        PP[1024 + cp] = bnb[768 + c] - bnm[768 + c] * s3;
        PP[1280 + cp] = Wout[c * 3];
        PP[1536 + cp] = Wout[c * 3 + 1];
        PP[1792 + cp] = Wout[c * 3 + 2];
    }
    grid.sync();

    // ---- phase A: degree atomics (2 grid-stride iterations)
    for (int e = gtid; e < EE; e += NN) {
        atomicAdd(&deg_out[src[e]], 1);
        atomicAdd(&deg_in[dst[e]], 1);
    }
    grid.sync();

    // ---- phase B: per-block exclusive scan of deg_in -> rp(partial), bsum
    {
        int v = deg_in[gtid];
        sh[tid] = v;
        __syncthreads();
#pragma unroll
        for (int off = 1; off < 256; off <<= 1) {
            int a = (tid >= off) ? sh[tid - off] : 0;
            __syncthreads();
            sh[tid] += a;
            __syncthreads();
        }
        rp[gtid] = sh[tid] - v;
        if (tid == 255) bsum[blockIdx.x] = sh[tid];
    }
    grid.sync();

    // ---- phase C: exclusive scan of bsum[544] (block 0 only)
    if (blockIdx.x == 0) {
        for (int i = tid; i < NBLK; i += 256) shS[i] = bsum[i];
        __syncthreads();
        int i0 = 3 * tid;
        int a0 = (i0 < NBLK) ? shS[i0] : 0;
        int a1 = (i0 + 1 < NBLK) ? shS[i0 + 1] : 0;
        int a2 = (i0 + 2 < NBLK) ? shS[i0 + 2] : 0;
        int S = a0 + a1 + a2;
        shT[tid] = S;
        __syncthreads();
#pragma unroll
        for (int off = 1; off < 256; off <<= 1) {
            int a = (tid >= off) ? shT[tid - off] : 0;
            __syncthreads();
            shT[tid] += a;
            __syncthreads();
        }
        int P = shT[tid] - S;                    // exclusive prefix of thread sums
        if (i0 < NBLK)     bsum[i0]     = P;
        if (i0 + 1 < NBLK) bsum[i0 + 1] = P + a0;
        if (i0 + 2 < NBLK) bsum[i0 + 2] = P + a0 + a1;
    }
    grid.sync();

    // ---- phase D: finalize rp/cursor + norm factors
    {
        int v = rp[gtid] + bsum[blockIdx.x];
        rp[gtid] = v;
        cursor[gtid] = v;
        if (gtid == 0) rp[NN] = EE;
        n_out[gtid] = rsqrtf((float)max(deg_out[gtid], 1));
        n_in[gtid]  = rsqrtf((float)max(deg_in[gtid], 1));
    }
    grid.sync();

    // ---- phase E: CSR fill
    for (int e = gtid; e < EE; e += NN) {
        int d = dst[e];
        int pos = atomicAdd(&cursor[d], 1);
        csr[pos] = src[e];
    }
    grid.sync();

    // ---- phase F: rowstats -> T
    {
        int r = gtid;
        int e0 = rp[r], e1 = rp[r + 1];
        float S0 = 0.f, S1 = 0.f, S2 = 0.f;
        for (int e = e0; e < e1; e++) {
            int s = csr[e];
            float sc = n_out[s];
            S0 = fmaf(sc, nf[2 * s], S0);
            S1 = fmaf(sc, nf[2 * s + 1], S1);
            S2 += sc;
        }
        float ni = n_in[r];
        T[3 * r]     = S0 * ni;
        T[3 * r + 1] = S1 * ni;
        T[3 * r + 2] = S2 * ni;
    }
}

// ---------------- conv1: cooperative y-build (scalar tables) + GEMM2 + Wout tile ----
__launch_bounds__(256)
__global__ void k_conv1(const float* __restrict__ T, const float* __restrict__ nf,
                        const float* __restrict__ TAB, const float* __restrict__ n_out,
                        const unsigned short* __restrict__ Wt2, const unsigned short* __restrict__ wot,
                        unsigned short* __restrict__ h1w, float* __restrict__ R3) {
    __shared__ unsigned char tileY[64 * 512];
    int lane = threadIdx.x & 63, wave = threadIdx.x >> 6;
    int wrow = blockIdx.x * 64;
    int rsel = lane & 15, kq = lane >> 4;

    // ---- phase 1: thread (wave,lane) builds channels wave*64..+63 of row lane
    {
        int wu = __builtin_amdgcn_readfirstlane(wave);   // wave-uniform -> SGPR
        const float* tb = TAB + wu * 64;
        int row = wrow + lane;
        float t0 = T[3 * row], t1 = T[3 * row + 1], t2 = T[3 * row + 2];
        float2 p = *(const float2*)(nf + 2 * (size_t)row);
        float f0 = p.x, f1 = p.y;
        float no = n_out[row];
        int sw = (lane & 7) << 4;
        unsigned char* wb = tileY + lane * 512;
#pragma unroll
        for (int jj = 0; jj < 8; jj++) {
            int co = jj * 8;
            f32x4 ew0a = *(const f32x4*)(tb + co),        ew0b = *(const f32x4*)(tb + co + 4);
            f32x4 ew1a = *(const f32x4*)(tb + 256 + co),  ew1b = *(const f32x4*)(tb + 256 + co + 4);
            f32x4 ew2a = *(const f32x4*)(tb + 512 + co),  ew2b = *(const f32x4*)(tb + 512 + co + 4);
            f32x4 c0a  = *(const f32x4*)(tb + 768 + co),  c0b  = *(const f32x4*)(tb + 768 + co + 4);
            f32x4 s1a  = *(const f32x4*)(tb + 1024 + co), s1b  = *(const f32x4*)(tb + 1024 + co + 4);
            f32x4 h1a  = *(const f32x4*)(tb + 1280 + co), h1b  = *(const f32x4*)(tb + 1280 + co + 4);
            f32x4 w0a  = *(const f32x4*)(tb + 1536 + co), w0b  = *(const f32x4*)(tb + 1536 + co + 4);
            f32x4 w1a  = *(const f32x4*)(tb + 1792 + co), w1b  = *(const f32x4*)(tb + 1792 + co + 4);
            f32x4 bea  = *(const f32x4*)(tb + 2048 + co), beb  = *(const f32x4*)(tb + 2048 + co + 4);
            u16x8 o;
#pragma unroll
            for (int j = 0; j < 4; j++) {
                float z = fmaf(t0, ew0a[j], fmaf(t1, ew1a[j], fmaf(t2, ew2a[j], c0a[j])));
                z = fmaxf(z, 0.f);
                z = fmaxf(fmaf(z, s1a[j], h1a[j]), 0.f);
                float yv = z + fmaf(f0, w0a[j], fmaf(f1, w1a[j], bea[j]));
                o[j] = bfbits(yv * no);
            }
#pragma unroll
            for (int j = 0; j < 4; j++) {
                float z = fmaf(t0, ew0b[j], fmaf(t1, ew1b[j], fmaf(t2, ew2b[j], c0b[j])));
                z = fmaxf(z, 0.f);
                z = fmaxf(fmaf(z, s1b[j], h1b[j]), 0.f);
                float yv = z + fmaf(f0, w0b[j], fmaf(f1, w1b[j], beb[j]));
                o[4 + j] = bfbits(yv * no);
            }
            int cbyte = (wu * 64 + co) * 2;
            *(u16x8*)(wb + (cbyte ^ sw)) = o;
        }
    }
    __syncthreads();

    // ---- phase 2: GEMM2 (tileY @ W2) + Wout residual tile (wave 0)
    bool w0w = (wave == 0);
    f32x4 acc[4][4];
    f32x4 acc3[4];
    f32x4 zero = {0.f, 0.f, 0.f, 0.f};
#pragma unroll
    for (int i = 0; i < 4; i++) {
        acc3[i] = zero;
#pragma unroll
        for (int j = 0; j < 4; j++) acc[i][j] = zero;
    }
#pragma unroll
    for (int kt = 0; kt < 8; kt++) {
        int cb = kt * 64 + kq * 16;
        int k0 = kt * 32 + kq * 8;
        bf16x8 afr[4];
#pragma unroll
        for (int mt = 0; mt < 4; mt++) {
            int ar = mt * 16 + rsel;
            u16x8 au = *(const u16x8*)(tileY + ar * 512 + (cb ^ ((ar & 7) << 4)));
            afr[mt] = __builtin_bit_cast(bf16x8, au);
        }
        bf16x8 bfr[4];
#pragma unroll
        for (int nt = 0; nt < 4; nt++) {
            u16x8 bu = *(const u16x8*)(Wt2 + (size_t)(wave * 64 + nt * 16 + rsel) * 256 + k0);
            bfr[nt] = __builtin_bit_cast(bf16x8, bu);
        }
        bf16x8 bw;
        if (w0w) {
            u16x8 bu = *(const u16x8*)(wot + (size_t)rsel * 256 + k0);
            bw = __builtin_bit_cast(bf16x8, bu);
        }
#pragma unroll
        for (int mt = 0; mt < 4; mt++) {
#pragma unroll
            for (int nt = 0; nt < 4; nt++)
                acc[mt][nt] = __builtin_amdgcn_mfma_f32_16x16x32_bf16(afr[mt], bfr[nt], acc[mt][nt], 0, 0, 0);
            if (w0w)
                acc3[mt] = __builtin_amdgcn_mfma_f32_16x16x32_bf16(afr[mt], bw, acc3[mt], 0, 0, 0);
        }
    }

    // permuted coalesced stores: channel c' = wave*64 + rsel*4 + nt
#pragma unroll
    for (int mt = 0; mt < 4; mt++) {
#pragma unroll
        for (int r = 0; r < 4; r++) {
            int row = wrow + mt * 16 + kq * 4 + r;
            u16x4 o;
#pragma unroll
            for (int nt = 0; nt < 4; nt++) o[nt] = bfbits(acc[mt][nt][r]);
            *(u16x4*)(h1w + (size_t)row * 256 + wave * 64 + rsel * 4) = o;
        }
    }

    // R3 from wave 0, lanes rsel<3
    if (w0w && rsel < 3) {
#pragma unroll
        for (int mt = 0; mt < 4; mt++)
#pragma unroll
            for (int r = 0; r < 4; r++) {
                int row = wrow + mt * 16 + kq * 4 + r;
                R3[(size_t)row * 3 + rsel] = acc3[mt][r] / n_out[row];
            }
    }
}

// ---------------- k_gconv: register gather + permuted bn/relu + pose dot (r10) ----
__launch_bounds__(256)
__global__ void k_gconv(const int* __restrict__ rp, const int* __restrict__ csr,
                        const float* __restrict__ n_in, const unsigned short* __restrict__ h1w,
                        const float* __restrict__ PP, const float* __restrict__ bout,
                        const float* __restrict__ R3, float* __restrict__ h3d) {
    int hw = threadIdx.x >> 5;        // 0..7 half-waves
    int l = threadIdx.x & 31;
    int c0 = l * 8;                   // 8 permuted channels per lane

    float bc[8], s0[8], h0[8], s1[8], h1v[8], w0[8], w1[8], w2[8];
#pragma unroll
    for (int j = 0; j < 8; j += 4) {
        *(float4*)(bc + j)  = *(const float4*)(PP + c0 + j);
        *(float4*)(s0 + j)  = *(const float4*)(PP + 256 + c0 + j);
        *(float4*)(h0 + j)  = *(const float4*)(PP + 512 + c0 + j);
        *(float4*)(s1 + j)  = *(const float4*)(PP + 768 + c0 + j);
        *(float4*)(h1v + j) = *(const float4*)(PP + 1024 + c0 + j);
        *(float4*)(w0 + j)  = *(const float4*)(PP + 1280 + c0 + j);
        *(float4*)(w1 + j)  = *(const float4*)(PP + 1536 + c0 + j);
        *(float4*)(w2 + j)  = *(const float4*)(PP + 1792 + c0 + j);
    }
    float b0 = bout[0], b1 = bout[1], b2v = bout[2];

    int rbase = blockIdx.x * 64 + hw * 8;
#pragma unroll 1
    for (int i = 0; i < 8; i++) {
        int row = rbase + i;
        int e0 = rp[row], e1 = rp[row + 1];
        float a[8] = {0.f, 0.f, 0.f, 0.f, 0.f, 0.f, 0.f, 0.f};
        for (int e = e0; e < e1; e++) {
            int s = csr[e];
            u16x8 v = *(const u16x8*)(h1w + ((size_t)s << 8) + c0);
#pragma unroll
            for (int j = 0; j < 8; j++) a[j] += bf2f(v[j]);
        }
        float ni = n_in[row];
        float p0 = 0.f, p1 = 0.f, p2 = 0.f;
#pragma unroll
        for (int j = 0; j < 8; j++) {
            float y = fmaf(a[j], ni, bc[j]);
            y = fmaxf(fmaf(y, s0[j], h0[j]), 0.f);
            y = fmaxf(fmaf(y, s1[j], h1v[j]), 0.f);
            p0 = fmaf(y, w0[j], p0);
            p1 = fmaf(y, w1[j], p1);
            p2 = fmaf(y, w2[j], p2);
        }
#pragma unroll
        for (int m = 1; m < 32; m <<= 1) {
            p0 += __shfl_xor(p0, m, 32);
            p1 += __shfl_xor(p1, m, 32);
            p2 += __shfl_xor(p2, m, 32);
        }
        if (l == 0) {
            size_t o = (size_t)row * 3;
            h3d[o]     = p0 + R3[o]     + b0;
            h3d[o + 1] = p1 + R3[o + 1] + b1;
            h3d[o + 2] = p2 + R3[o + 2] + b2v;
        }
    }
}

// ---------------- fused classification head: 1 wave per block, 16 graphs ----------
__launch_bounds__(64)
__global__ void k_head(const int* __restrict__ n2g, const float* __restrict__ h3d,
                       const float* __restrict__ Wci, const float* __restrict__ bci,
                       const unsigned short* __restrict__ wta, const float* __restrict__ ba,
                       const unsigned short* __restrict__ wtb, const float* __restrict__ bb,
                       const unsigned short* __restrict__ wtcls, const float* __restrict__ bcls,
                       const float* __restrict__ bns, const float* __restrict__ bnh,
                       float* __restrict__ label) {
    __shared__ unsigned char tileA[8192];
    __shared__ unsigned char tileB[8192];
    int lane = threadIdx.x;
    int wrow = blockIdx.x * 16;
    int rsel = lane & 15, kq = lane >> 4;
    int g = wrow + rsel;

    int lo = 0, hi = NN;
    while (lo < hi) { int mid = (lo + hi) >> 1; if (n2g[mid] < g) lo = mid + 1; else hi = mid; }
    int s = lo;
    hi = NN;
    while (lo < hi) { int mid = (lo + hi) >> 1; if (n2g[mid] < g + 1) lo = mid + 1; else hi = mid; }
    int e = lo;
    float m0 = 0.f, m1 = 0.f, m2 = 0.f;
    for (int j = s; j < e; j++) {
        m0 += h3d[(size_t)j * 3];
        m1 += h3d[(size_t)j * 3 + 1];
        m2 += h3d[(size_t)j * 3 + 2];
    }
    float inv = 1.f / fmaxf((float)(e - s), 1.f);
    m0 *= inv; m1 *= inv; m2 *= inv;

    f32x4 zero = {0.f, 0.f, 0.f, 0.f};
    f32x4 acc[16];
#pragma unroll
    for (int i = 0; i < 16; i++) acc[i] = zero;

    // stage 1: z1 = relu(bn4(z0 @ Wa + ba)), z0 built on the fly
#pragma unroll
    for (int kt = 0; kt < 8; kt++) {
        int k0 = kt * 32 + kq * 8;
        u16x8 au;
#pragma unroll
        for (int j = 0; j < 8; j++)
            au[j] = f2bf(fmaf(m0, Wci[k0 + j], fmaf(m1, Wci[256 + k0 + j],
                         fmaf(m2, Wci[512 + k0 + j], bci[k0 + j]))));
        bf16x8 af = __builtin_bit_cast(bf16x8, au);
#pragma unroll
        for (int nt = 0; nt < 16; nt++) {
            u16x8 bu = *(const u16x8*)(wta + (size_t)(nt * 16 + rsel) * 256 + k0);
            acc[nt] = __builtin_amdgcn_mfma_f32_16x16x32_bf16(af, __builtin_bit_cast(bf16x8, bu), acc[nt], 0, 0, 0);
        }
    }
#pragma unroll
    for (int nt = 0; nt < 16; nt++) {
        int col = nt * 16 + rsel;
        float bcv = ba[col];
        float sc = bns[4 * 256 + col], h = bnh[4 * 256 + col];
#pragma unroll
        for (int r = 0; r < 4; r++) {
            float y = fmaxf(fmaf(acc[nt][r] + bcv, sc, h), 0.f);
            int rr = kq * 4 + r;
            *(unsigned short*)(tileA + rr * 512 + ((col * 2) ^ ((rr & 7) << 4))) = f2bf(y);
        }
    }

    // stage 2: z2 = relu(bn5(z1 @ Wb + bb))
#pragma unroll
    for (int i = 0; i < 16; i++) acc[i] = zero;
#pragma unroll
    for (int kt = 0; kt < 8; kt++) {
        int cb = kt * 64 + kq * 16;
        u16x8 au = *(const u16x8*)(tileA + rsel * 512 + (cb ^ ((rsel & 7) << 4)));
        bf16x8 af = __builtin_bit_cast(bf16x8, au);
        int k0 = kt * 32 + kq * 8;
#pragma unroll
        for (int nt = 0; nt < 16; nt++) {
            u16x8 bu = *(const u16x8*)(wtb + (size_t)(nt * 16 + rsel) * 256 + k0);
            acc[nt] = __builtin_amdgcn_mfma_f32_16x16x32_bf16(af, __builtin_bit_cast(bf16x8, bu), acc[nt], 0, 0, 0);
        }
    }
#pragma unroll
    for (int nt = 0; nt < 16; nt++) {
        int col = nt * 16 + rsel;
        float bcv = bb[col];
        float sc = bns[5 * 256 + col], h = bnh[5 * 256 + col];
#pragma unroll
        for (int r = 0; r < 4; r++) {
            float y = fmaxf(fmaf(acc[nt][r] + bcv, sc, h), 0.f);
            int rr = kq * 4 + r;
            *(unsigned short*)(tileB + rr * 512 + ((col * 2) ^ ((rr & 7) << 4))) = f2bf(y);
        }
    }

    // stage 3: label = z2 @ Wcls + bcls (60 cols)
    f32x4 acc3[4];
#pragma unroll
    for (int i = 0; i < 4; i++) acc3[i] = zero;
#pragma unroll
    for (int kt = 0; kt < 8; kt++) {
        int cb = kt * 64 + kq * 16;
        u16x8 au = *(const u16x8*)(tileB + rsel * 512 + (cb ^ ((rsel & 7) << 4)));
        bf16x8 af = __builtin_bit_cast(bf16x8, au);
        int k0 = kt * 32 + kq * 8;
#pragma unroll
        for (int nt = 0; nt < 4; nt++) {
            u16x8 bu = *(const u16x8*)(wtcls + (size_t)(nt * 16 + rsel) * 256 + k0);
            acc3[nt] = __builtin_amdgcn_mfma_f32_16x16x32_bf16(af, __builtin_bit_cast(bf16x8, bu), acc3[nt], 0, 0, 0);
        }
    }
    int rowb = wrow + kq * 4;
#pragma unroll
    for (int nt = 0; nt < 4; nt++) {
        int col = nt * 16 + rsel;
        if (col < 60) {
            float bcv = bcls[col];
#pragma unroll
            for (int r = 0; r < 4; r++)
                label[(size_t)(rowb + r) * 60 + col] = acc3[nt][r] + bcv;
        }
    }
}

// ---------------- launch ----------------
extern "C" void kernel_launch(void* const* d_in, const int* in_sizes, int n_in,
                              void* d_out, int out_size, void* d_ws, size_t ws_size,
                              hipStream_t stream) {
    const float* nf   = (const float*)d_in[0];
    const int* src    = (const int*)d_in[1];
    const int* dst    = (const int*)d_in[2];
    const int* n2g    = (const int*)d_in[3];
    const float* Wemb = (const float*)d_in[4];
    const float* bemb = (const float*)d_in[5];
    const float* Wc1  = (const float*)d_in[6];
    const float* bc1  = (const float*)d_in[7];
    const float* Wc2  = (const float*)d_in[8];
    const float* bc2  = (const float*)d_in[9];
    const float* bng  = (const float*)d_in[10];
    const float* bnb  = (const float*)d_in[11];
    const float* bnm  = (const float*)d_in[12];
    const float* bnv  = (const float*)d_in[13];
    const float* Wout = (const float*)d_in[14];
    const float* bout = (const float*)d_in[15];
    const float* Wci  = (const float*)d_in[16];
    const float* bci  = (const float*)d_in[17];
    const float* Wb3a = (const float*)d_in[18];
    const float* bb3a = (const float*)d_in[19];
    const float* Wb3b = (const float*)d_in[20];
    const float* bb3b = (const float*)d_in[21];
    const float* Wcls = (const float*)d_in[22];
    const float* bcls = (const float*)d_in[23];

    char* ws = (char*)d_ws;
    int* deg_out = (int*)(ws + OFF_DEG_OUT);
    int* deg_in  = (int*)(ws + OFF_DEG_IN);
    float* T     = (float*)(ws + OFF_T);
    float* n_out = (float*)(ws + OFF_NOUT);
    float* n_inp = (float*)(ws + OFF_NIN);
    int* row_ptr = (int*)(ws + OFF_ROWPTR);
    int* cursor  = (int*)(ws + OFF_CURSOR);
    int* csr_src = (int*)(ws + OFF_CSRS);
    int* bsum    = (int*)(ws + OFF_BSUM);
    unsigned short* wt2   = (unsigned short*)(ws + OFF_WT2);
    unsigned short* wta   = (unsigned short*)(ws + OFF_WTA);
    unsigned short* wtb   = (unsigned short*)(ws + OFF_WTB);
    unsigned short* wtcls = (unsigned short*)(ws + OFF_WTCLS);
    unsigned short* wot   = (unsigned short*)(ws + OFF_WOT);
    float* bns = (float*)(ws + OFF_BNS);
    float* bnh = (float*)(ws + OFF_BNH);
    float* TAB = (float*)(ws + OFF_TAB);
    float* PP  = (float*)(ws + OFF_PP);
    float* R3  = (float*)(ws + OFF_R3);
    unsigned short* h1w = (unsigned short*)(ws + OFF_H1W);

    float* h3d_out   = (float*)d_out;
    float* label_out = (float*)d_out + (size_t)NN * 3;

    void* args[] = {
        (void*)&src, (void*)&dst, (void*)&nf,
        (void*)&deg_out, (void*)&deg_in, (void*)&row_ptr, (void*)&cursor, (void*)&csr_src,
        (void*)&n_out, (void*)&n_inp, (void*)&bsum, (void*)&T,
        (void*)&Wc2, (void*)&Wb3a, (void*)&Wb3b,
        (void*)&wt2, (void*)&wta, (void*)&wtb,
        (void*)&Wcls, (void*)&wtcls,
        (void*)&bng, (void*)&bnb, (void*)&bnm, (void*)&bnv,
        (void*)&bns, (void*)&bnh,
        (void*)&Wout, (void*)&wot,
        (void*)&Wemb, (void*)&bemb,
        (void*)&Wc1, (void*)&bc1, (void*)&bc2,
        (void*)&TAB, (void*)&PP
    };
    hipLaunchCooperativeKernel((const void*)k_gprep, dim3(NBLK), dim3(256), args, 0, stream);

    k_conv1<<<NN / 64, 256, 0, stream>>>(T, nf, TAB, n_out, wt2, wot, h1w, R3);
    k_gconv<<<NN / 64, 256, 0, stream>>>(row_ptr, csr_src, n_inp, h1w, PP, bout, R3, h3d_out);
    k_head<<<GG / 16, 64, 0, stream>>>(n2g, h3d_out, Wci, bci, wta, bb3a, wtb, bb3b,
                                       wtcls, bcls, bns, bnh, label_out);
}

// Round 14
// 223.627 us; speedup vs baseline: 2.6276x; 2.6276x over previous
//
#include <hip/hip_runtime.h>

// SimplePoseGNN on MI355X — round 14 (revert r13; r10 config + merged deg/prep).
// fp32 in/out; internal bf16 + fp32 accumulation; bf16 MFMA GEMMs.
// conv1 (r10): cooperative y-build w/ scalar tables, swizzled tileY, GEMM2 + Wout
// residual tile, channel-permuted 8B stores. k_gconv (r10): half-wave per row,
// params in VGPRs. k_head: 64-thread blocks. Graph mean via binary search.
// k_degprep: degree atomics + ALL table prep in ONE launch (blockIdx dispatch).

#define NN 139264
#define EE 278528
#define GG 8192
#define NBLK 544    // NN/256
#define EBLK 1088   // EE/256

typedef float f32x4 __attribute__((ext_vector_type(4)));
typedef __bf16 bf16x8 __attribute__((ext_vector_type(8)));
typedef unsigned short u16x8 __attribute__((ext_vector_type(8)));
typedef unsigned short u16x4 __attribute__((ext_vector_type(4)));

__device__ __forceinline__ float bf2f(unsigned short u) {
    unsigned int i = ((unsigned int)u) << 16;
    float f;
    __builtin_memcpy(&f, &i, 4);
    return f;
}
__device__ __forceinline__ unsigned short f2bf(float f) {
    unsigned int i;
    __builtin_memcpy(&i, &f, 4);
    i += 0x7fffu + ((i >> 16) & 1u);   // round-to-nearest-even
    return (unsigned short)(i >> 16);
}
__device__ __forceinline__ unsigned short bfbits(float f) {
    __bf16 b = (__bf16)f;
    return __builtin_bit_cast(unsigned short, b);
}

// ---------------- workspace layout (bytes) ----------------
#define OFF_DEG_OUT ((size_t)0)
#define OFF_DEG_IN  ((size_t)557056)
#define ZERO_BYTES  ((size_t)1114112)
#define OFF_T       ((size_t)1114112)
#define OFF_NOUT    ((size_t)2785280)
#define OFF_NIN     ((size_t)3342336)
#define OFF_ROWPTR  ((size_t)3899392)
#define OFF_CURSOR  ((size_t)4460544)
#define OFF_CSRS    ((size_t)5017600)
#define OFF_WT2     ((size_t)6131712)
#define OFF_WTA     ((size_t)6262784)
#define OFF_WTB     ((size_t)6393856)
#define OFF_WTCLS   ((size_t)6524928)
#define OFF_WOT     ((size_t)6557696)
#define OFF_BNS     ((size_t)6565888)
#define OFF_BNH     ((size_t)6572032)
#define OFF_TAB     ((size_t)6578176)
#define OFF_PP      ((size_t)6587392)
#define OFF_BSUM    ((size_t)6595584)
#define OFF_R3      ((size_t)6599680)
#define OFF_H1W     ((size_t)8270848)
// total ~79.6 MB

// ---------------- merged degree + table prep (one launch) ----------------
// blocks [0,1088): degree atomics.  blocks [1088,1944): table prep, compacted:
//   +0..767   : wt2/wta/wtb transposes (256 blocks each)
//   +768..831 : tcls
//   +832..837 : bns/bnh
//   +838..853 : wot
//   +854      : TAB (256-iter dots)
//   +855      : PP
__global__ void k_degprep(const int* __restrict__ src, const int* __restrict__ dst,
                          int* __restrict__ deg_out, int* __restrict__ deg_in,
                          const float* __restrict__ Wc2, const float* __restrict__ Wb3a,
                          const float* __restrict__ Wb3b,
                          unsigned short* __restrict__ wt2, unsigned short* __restrict__ wta,
                          unsigned short* __restrict__ wtb,
                          const float* __restrict__ wcls, unsigned short* __restrict__ tcls,
                          const float* __restrict__ g, const float* __restrict__ b,
                          const float* __restrict__ m, const float* __restrict__ v,
                          float* __restrict__ bns, float* __restrict__ bnh,
                          const float* __restrict__ Wout, unsigned short* __restrict__ wot,
                          const float* __restrict__ Wemb, const float* __restrict__ bemb,
                          const float* __restrict__ Wc1, const float* __restrict__ bc1,
                          const float* __restrict__ bc2,
                          float* __restrict__ TAB, float* __restrict__ PP) {
    int bid = blockIdx.x, tid = threadIdx.x;
    if (bid < EBLK) {
        int e = bid * 256 + tid;
        atomicAdd(&deg_out[src[e]], 1);
        atomicAdd(&deg_in[dst[e]], 1);
        return;
    }
    int pb = bid - EBLK;
    if (pb < 768) {
        int y = pb >> 8;
        int t = (pb & 255) * 256 + tid;
        int k = t >> 8, n = t & 255;
        const float* w = (y == 0) ? Wc2 : (y == 1) ? Wb3a : Wb3b;
        unsigned short* o = (y == 0) ? wt2 : (y == 1) ? wta : wtb;
        o[n * 256 + k] = f2bf(w[t]);
        return;
    }
    pb -= 768;
    if (pb < 64) {
        int t = pb * 256 + tid;
        int n = t >> 8, k = t & 255;
        tcls[t] = (n < 60) ? f2bf(wcls[k * 60 + n]) : (unsigned short)0;
        return;
    }
    pb -= 64;
    if (pb < 6) {
        int t = pb * 256 + tid;
        float inv = rsqrtf(v[t] + 1e-5f);
        float s = g[t] * inv;
        bns[t] = s;
        bnh[t] = b[t] - m[t] * s;
        return;
    }
    pb -= 6;
    if (pb < 16) {
        int t = pb * 256 + tid;
        int n = t >> 8, k = t & 255;
        wot[t] = (n < 3) ? f2bf(Wout[k * 3 + n]) : (unsigned short)0;
        return;
    }
    pb -= 16;
    if (pb == 0) {
        int c = tid;
        float inv0 = rsqrtf(v[c] + 1e-5f);
        float s0 = g[c] * inv0;
        float h0 = b[c] - m[c] * s0;
        float e0 = 0.f, e1 = 0.f, e2 = 0.f;
        for (int k = 0; k < 256; k++) {
            float w = Wc1[k * 256 + c];
            e0 = fmaf(Wemb[k], w, e0);
            e1 = fmaf(Wemb[256 + k], w, e1);
            e2 = fmaf(bemb[k], w, e2);
        }
        TAB[c]        = e0 * s0;
        TAB[256 + c]  = e1 * s0;
        TAB[512 + c]  = e2 * s0;
        TAB[768 + c]  = fmaf(bc1[c], s0, h0);
        float inv1 = rsqrtf(v[256 + c] + 1e-5f);
        float s1 = g[256 + c] * inv1;
        TAB[1024 + c] = s1;
        TAB[1280 + c] = b[256 + c] - m[256 + c] * s1;
        TAB[1536 + c] = Wemb[c];
        TAB[1792 + c] = Wemb[256 + c];
        TAB[2048 + c] = bemb[c];
        return;
    }
    {   // PP
        int cp = tid;
        int w = cp >> 6, rs = (cp >> 2) & 15, nt = cp & 3;
        int c = w * 64 + nt * 16 + rs;
        PP[cp] = bc2[c];
        float inv2 = rsqrtf(v[512 + c] + 1e-5f);
        float s2 = g[512 + c] * inv2;
        PP[256 + cp] = s2;
        PP[512 + cp] = b[512 + c] - m[512 + c] * s2;
        float inv3 = rsqrtf(v[768 + c] + 1e-5f);
        float s3 = g[768 + c] * inv3;
        PP[768 + cp] = s3;
        PP[1024 + cp] = b[768 + c] - m[768 + c] * s3;
        PP[1280 + cp] = Wout[c * 3];
        PP[1536 + cp] = Wout[c * 3 + 1];
        PP[1792 + cp] = Wout[c * 3 + 2];
    }
}

// ---------------- graph scans ----------------

__global__ void k_scan1(const int* __restrict__ deg, int* __restrict__ part, int* __restrict__ bsum) {
    __shared__ int sh[256];
    int t = threadIdx.x, gid = blockIdx.x * 256 + t;
    int v = deg[gid];
    sh[t] = v;
    __syncthreads();
#pragma unroll
    for (int off = 1; off < 256; off <<= 1) {
        int a = (t >= off) ? sh[t - off] : 0;
        __syncthreads();
        sh[t] += a;
        __syncthreads();
    }
    part[gid] = sh[t] - v;
    if (t == 255) bsum[blockIdx.x] = sh[t];
}

__global__ void k_scan2(int* __restrict__ bsum) {
    __shared__ int sh[1024];
    int t = threadIdx.x;
    int v = (t < NBLK) ? bsum[t] : 0;
    sh[t] = v;
    __syncthreads();
#pragma unroll
    for (int off = 1; off < 1024; off <<= 1) {
        int a = (t >= off) ? sh[t - off] : 0;
        __syncthreads();
        sh[t] += a;
        __syncthreads();
    }
    if (t < NBLK) bsum[t] = sh[t] - v;
}

__global__ void k_scan3(int* __restrict__ rp, const int* __restrict__ bsum, int* __restrict__ cursor,
                        const int* __restrict__ dego, const int* __restrict__ degi,
                        float* __restrict__ n_out, float* __restrict__ n_in) {
    int t = threadIdx.x, gid = blockIdx.x * 256 + t;
    int v = rp[gid] + bsum[blockIdx.x];
    rp[gid] = v;
    cursor[gid] = v;
    if (gid == 0) rp[NN] = EE;
    n_out[gid] = rsqrtf((float)max(dego[gid], 1));
    n_in[gid]  = rsqrtf((float)max(degi[gid], 1));
}

__global__ void k_fill(const int* __restrict__ src, const int* __restrict__ dst,
                       int* __restrict__ cursor, int* __restrict__ csr) {
    int e = blockIdx.x * 256 + threadIdx.x;
    int d = dst[e];
    int pos = atomicAdd(&cursor[d], 1);
    csr[pos] = src[e];
}

// per-row conv1 stats: T[r] = n_in[r] * { Σ sc*nf0, Σ sc*nf1, Σ sc },  sc = n_out[src]
__global__ void k_rowstats(const int* __restrict__ rp, const int* __restrict__ csr,
                           const float* __restrict__ n_out, const float* __restrict__ n_in,
                           const float* __restrict__ nf, float* __restrict__ T) {
    int r = blockIdx.x * 256 + threadIdx.x;
    int e0 = rp[r], e1 = rp[r + 1];
    float S0 = 0.f, S1 = 0.f, S2 = 0.f;
    for (int e = e0; e < e1; e++) {
        int s = csr[e];
        float sc = n_out[s];
        S0 = fmaf(sc, nf[2 * s], S0);
        S1 = fmaf(sc, nf[2 * s + 1], S1);
        S2 += sc;
    }
    float ni = n_in[r];
    T[3 * r]     = S0 * ni;
    T[3 * r + 1] = S1 * ni;
    T[3 * r + 2] = S2 * ni;
}

// ---------------- conv1: cooperative y-build (scalar tables) + GEMM2 + Wout tile ----
__launch_bounds__(256)
__global__ void k_conv1(const float* __restrict__ T, const float* __restrict__ nf,
                        const float* __restrict__ TAB, const float* __restrict__ n_out,
                        const unsigned short* __restrict__ Wt2, const unsigned short* __restrict__ wot,
                        unsigned short* __restrict__ h1w, float* __restrict__ R3) {
    __shared__ unsigned char tileY[64 * 512];
    int lane = threadIdx.x & 63, wave = threadIdx.x >> 6;
    int wrow = blockIdx.x * 64;
    int rsel = lane & 15, kq = lane >> 4;

    // ---- phase 1: thread (wave,lane) builds channels wave*64..+63 of row lane
    {
        int wu = __builtin_amdgcn_readfirstlane(wave);   // wave-uniform -> SGPR
        const float* tb = TAB + wu * 64;
        int row = wrow + lane;
        float t0 = T[3 * row], t1 = T[3 * row + 1], t2 = T[3 * row + 2];
        float2 p = *(const float2*)(nf + 2 * (size_t)row);
        float f0 = p.x, f1 = p.y;
        float no = n_out[row];
        int sw = (lane & 7) << 4;
        unsigned char* wb = tileY + lane * 512;
#pragma unroll
        for (int jj = 0; jj < 8; jj++) {
            int co = jj * 8;
            f32x4 ew0a = *(const f32x4*)(tb + co),        ew0b = *(const f32x4*)(tb + co + 4);
            f32x4 ew1a = *(const f32x4*)(tb + 256 + co),  ew1b = *(const f32x4*)(tb + 256 + co + 4);
            f32x4 ew2a = *(const f32x4*)(tb + 512 + co),  ew2b = *(const f32x4*)(tb + 512 + co + 4);
            f32x4 c0a  = *(const f32x4*)(tb + 768 + co),  c0b  = *(const f32x4*)(tb + 768 + co + 4);
            f32x4 s1a  = *(const f32x4*)(tb + 1024 + co), s1b  = *(const f32x4*)(tb + 1024 + co + 4);
            f32x4 h1a  = *(const f32x4*)(tb + 1280 + co), h1b  = *(const f32x4*)(tb + 1280 + co + 4);
            f32x4 w0a  = *(const f32x4*)(tb + 1536 + co), w0b  = *(const f32x4*)(tb + 1536 + co + 4);
            f32x4 w1a  = *(const f32x4*)(tb + 1792 + co), w1b  = *(const f32x4*)(tb + 1792 + co + 4);
            f32x4 bea  = *(const f32x4*)(tb + 2048 + co), beb  = *(const f32x4*)(tb + 2048 + co + 4);
            u16x8 o;
#pragma unroll
            for (int j = 0; j < 4; j++) {
                float z = fmaf(t0, ew0a[j], fmaf(t1, ew1a[j], fmaf(t2, ew2a[j], c0a[j])));
                z = fmaxf(z, 0.f);
                z = fmaxf(fmaf(z, s1a[j], h1a[j]), 0.f);
                float yv = z + fmaf(f0, w0a[j], fmaf(f1, w1a[j], bea[j]));
                o[j] = bfbits(yv * no);
            }
#pragma unroll
            for (int j = 0; j < 4; j++) {
                float z = fmaf(t0, ew0b[j], fmaf(t1, ew1b[j], fmaf(t2, ew2b[j], c0b[j])));
                z = fmaxf(z, 0.f);
                z = fmaxf(fmaf(z, s1b[j], h1b[j]), 0.f);
                float yv = z + fmaf(f0, w0b[j], fmaf(f1, w1b[j], beb[j]));
                o[4 + j] = bfbits(yv * no);
            }
            int cbyte = (wu * 64 + co) * 2;
            *(u16x8*)(wb + (cbyte ^ sw)) = o;
        }
    }
    __syncthreads();

    // ---- phase 2: GEMM2 (tileY @ W2) + Wout residual tile (wave 0)
    bool w0w = (wave == 0);
    f32x4 acc[4][4];
    f32x4 acc3[4];
    f32x4 zero = {0.f, 0.f, 0.f, 0.f};
#pragma unroll
    for (int i = 0; i < 4; i++) {
        acc3[i] = zero;
#pragma unroll
        for (int j = 0; j < 4; j++) acc[i][j] = zero;
    }
#pragma unroll
    for (int kt = 0; kt < 8; kt++) {
        int cb = kt * 64 + kq * 16;
        int k0 = kt * 32 + kq * 8;
        bf16x8 afr[4];
#pragma unroll
        for (int mt = 0; mt < 4; mt++) {
            int ar = mt * 16 + rsel;
            u16x8 au = *(const u16x8*)(tileY + ar * 512 + (cb ^ ((ar & 7) << 4)));
            afr[mt] = __builtin_bit_cast(bf16x8, au);
        }
        bf16x8 bfr[4];
#pragma unroll
        for (int nt = 0; nt < 4; nt++) {
            u16x8 bu = *(const u16x8*)(Wt2 + (size_t)(wave * 64 + nt * 16 + rsel) * 256 + k0);
            bfr[nt] = __builtin_bit_cast(bf16x8, bu);
        }
        bf16x8 bw;
        if (w0w) {
            u16x8 bu = *(const u16x8*)(wot + (size_t)rsel * 256 + k0);
            bw = __builtin_bit_cast(bf16x8, bu);
        }
#pragma unroll
        for (int mt = 0; mt < 4; mt++) {
#pragma unroll
            for (int nt = 0; nt < 4; nt++)
                acc[mt][nt] = __builtin_amdgcn_mfma_f32_16x16x32_bf16(afr[mt], bfr[nt], acc[mt][nt], 0, 0, 0);
            if (w0w)
                acc3[mt] = __builtin_amdgcn_mfma_f32_16x16x32_bf16(afr[mt], bw, acc3[mt], 0, 0, 0);
        }
    }

    // permuted coalesced stores: channel c' = wave*64 + rsel*4 + nt
#pragma unroll
    for (int mt = 0; mt < 4; mt++) {
#pragma unroll
        for (int r = 0; r < 4; r++) {
            int row = wrow + mt * 16 + kq * 4 + r;
            u16x4 o;
#pragma unroll
            for (int nt = 0; nt < 4; nt++) o[nt] = bfbits(acc[mt][nt][r]);
            *(u16x4*)(h1w + (size_t)row * 256 + wave * 64 + rsel * 4) = o;
        }
    }

    // R3 from wave 0, lanes rsel<3
    if (w0w && rsel < 3) {
#pragma unroll
        for (int mt = 0; mt < 4; mt++)
#pragma unroll
            for (int r = 0; r < 4; r++) {
                int row = wrow + mt * 16 + kq * 4 + r;
                R3[(size_t)row * 3 + rsel] = acc3[mt][r] / n_out[row];
            }
    }
}

// ---------------- k_gconv: register gather + permuted bn/relu + pose dot (r10) ----
__launch_bounds__(256)
__global__ void k_gconv(const int* __restrict__ rp, const int* __restrict__ csr,
                        const float* __restrict__ n_in, const unsigned short* __restrict__ h1w,
                        const float* __restrict__ PP, const float* __restrict__ bout,
                        const float* __restrict__ R3, float* __restrict__ h3d) {
    int hw = threadIdx.x >> 5;        // 0..7 half-waves
    int l = threadIdx.x & 31;
    int c0 = l * 8;                   // 8 permuted channels per lane

    float bc[8], s0[8], h0[8], s1[8], h1v[8], w0[8], w1[8], w2[8];
#pragma unroll
    for (int j = 0; j < 8; j += 4) {
        *(float4*)(bc + j)  = *(const float4*)(PP + c0 + j);
        *(float4*)(s0 + j)  = *(const float4*)(PP + 256 + c0 + j);
        *(float4*)(h0 + j)  = *(const float4*)(PP + 512 + c0 + j);
        *(float4*)(s1 + j)  = *(const float4*)(PP + 768 + c0 + j);
        *(float4*)(h1v + j) = *(const float4*)(PP + 1024 + c0 + j);
        *(float4*)(w0 + j)  = *(const float4*)(PP + 1280 + c0 + j);
        *(float4*)(w1 + j)  = *(const float4*)(PP + 1536 + c0 + j);
        *(float4*)(w2 + j)  = *(const float4*)(PP + 1792 + c0 + j);
    }
    float b0 = bout[0], b1 = bout[1], b2v = bout[2];

    int rbase = blockIdx.x * 64 + hw * 8;
#pragma unroll 1
    for (int i = 0; i < 8; i++) {
        int row = rbase + i;
        int e0 = rp[row], e1 = rp[row + 1];
        float a[8] = {0.f, 0.f, 0.f, 0.f, 0.f, 0.f, 0.f, 0.f};
        for (int e = e0; e < e1; e++) {
            int s = csr[e];
            u16x8 v = *(const u16x8*)(h1w + ((size_t)s << 8) + c0);
#pragma unroll
            for (int j = 0; j < 8; j++) a[j] += bf2f(v[j]);
        }
        float ni = n_in[row];
        float p0 = 0.f, p1 = 0.f, p2 = 0.f;
#pragma unroll
        for (int j = 0; j < 8; j++) {
            float y = fmaf(a[j], ni, bc[j]);
            y = fmaxf(fmaf(y, s0[j], h0[j]), 0.f);
            y = fmaxf(fmaf(y, s1[j], h1v[j]), 0.f);
            p0 = fmaf(y, w0[j], p0);
            p1 = fmaf(y, w1[j], p1);
            p2 = fmaf(y, w2[j], p2);
        }
#pragma unroll
        for (int m = 1; m < 32; m <<= 1) {
            p0 += __shfl_xor(p0, m, 32);
            p1 += __shfl_xor(p1, m, 32);
            p2 += __shfl_xor(p2, m, 32);
        }
        if (l == 0) {
            size_t o = (size_t)row * 3;
            h3d[o]     = p0 + R3[o]     + b0;
            h3d[o + 1] = p1 + R3[o + 1] + b1;
            h3d[o + 2] = p2 + R3[o + 2] + b2v;
        }
    }
}

// ---------------- fused classification head: 1 wave per block, 16 graphs ----------
__launch_bounds__(64)
__global__ void k_head(const int* __restrict__ n2g, const float* __restrict__ h3d,
                       const float* __restrict__ Wci, const float* __restrict__ bci,
                       const unsigned short* __restrict__ wta, const float* __restrict__ ba,
                       const unsigned short* __restrict__ wtb, const float* __restrict__ bb,
                       const unsigned short* __restrict__ wtcls, const float* __restrict__ bcls,
                       const float* __restrict__ bns, const float* __restrict__ bnh,
                       float* __restrict__ label) {
    __shared__ unsigned char tileA[8192];
    __shared__ unsigned char tileB[8192];
    int lane = threadIdx.x;
    int wrow = blockIdx.x * 16;
    int rsel = lane & 15, kq = lane >> 4;
    int g = wrow + rsel;

    int lo = 0, hi = NN;
    while (lo < hi) { int mid = (lo + hi) >> 1; if (n2g[mid] < g) lo = mid + 1; else hi = mid; }
    int s = lo;
    hi = NN;
    while (lo < hi) { int mid = (lo + hi) >> 1; if (n2g[mid] < g + 1) lo = mid + 1; else hi = mid; }
    int e = lo;
    float m0 = 0.f, m1 = 0.f, m2 = 0.f;
    for (int j = s; j < e; j++) {
        m0 += h3d[(size_t)j * 3];
        m1 += h3d[(size_t)j * 3 + 1];
        m2 += h3d[(size_t)j * 3 + 2];
    }
    float inv = 1.f / fmaxf((float)(e - s), 1.f);
    m0 *= inv; m1 *= inv; m2 *= inv;

    f32x4 zero = {0.f, 0.f, 0.f, 0.f};
    f32x4 acc[16];
#pragma unroll
    for (int i = 0; i < 16; i++) acc[i] = zero;

    // stage 1: z1 = relu(bn4(z0 @ Wa + ba)), z0 built on the fly
#pragma unroll
    for (int kt = 0; kt < 8; kt++) {
        int k0 = kt * 32 + kq * 8;
        u16x8 au;
#pragma unroll
        for (int j = 0; j < 8; j++)
            au[j] = f2bf(fmaf(m0, Wci[k0 + j], fmaf(m1, Wci[256 + k0 + j],
                         fmaf(m2, Wci[512 + k0 + j], bci[k0 + j]))));
        bf16x8 af = __builtin_bit_cast(bf16x8, au);
#pragma unroll
        for (int nt = 0; nt < 16; nt++) {
            u16x8 bu = *(const u16x8*)(wta + (size_t)(nt * 16 + rsel) * 256 + k0);
            acc[nt] = __builtin_amdgcn_mfma_f32_16x16x32_bf16(af, __builtin_bit_cast(bf16x8, bu), acc[nt], 0, 0, 0);
        }
    }
#pragma unroll
    for (int nt = 0; nt < 16; nt++) {
        int col = nt * 16 + rsel;
        float bcv = ba[col];
        float sc = bns[4 * 256 + col], h = bnh[4 * 256 + col];
#pragma unroll
        for (int r = 0; r < 4; r++) {
            float y = fmaxf(fmaf(acc[nt][r] + bcv, sc, h), 0.f);
            int rr = kq * 4 + r;
            *(unsigned short*)(tileA + rr * 512 + ((col * 2) ^ ((rr & 7) << 4))) = f2bf(y);
        }
    }

    // stage 2: z2 = relu(bn5(z1 @ Wb + bb))
#pragma unroll
    for (int i = 0; i < 16; i++) acc[i] = zero;
#pragma unroll
    for (int kt = 0; kt < 8; kt++) {
        int cb = kt * 64 + kq * 16;
        u16x8 au = *(const u16x8*)(tileA + rsel * 512 + (cb ^ ((rsel & 7) << 4)));
        bf16x8 af = __builtin_bit_cast(bf16x8, au);
        int k0 = kt * 32 + kq * 8;
#pragma unroll
        for (int nt = 0; nt < 16; nt++) {
            u16x8 bu = *(const u16x8*)(wtb + (size_t)(nt * 16 + rsel) * 256 + k0);
            acc[nt] = __builtin_amdgcn_mfma_f32_16x16x32_bf16(af, __builtin_bit_cast(bf16x8, bu), acc[nt], 0, 0, 0);
        }
    }
#pragma unroll
    for (int nt = 0; nt < 16; nt++) {
        int col = nt * 16 + rsel;
        float bcv = bb[col];
        float sc = bns[5 * 256 + col], h = bnh[5 * 256 + col];
#pragma unroll
        for (int r = 0; r < 4; r++) {
            float y = fmaxf(fmaf(acc[nt][r] + bcv, sc, h), 0.f);
            int rr = kq * 4 + r;
            *(unsigned short*)(tileB + rr * 512 + ((col * 2) ^ ((rr & 7) << 4))) = f2bf(y);
        }
    }

    // stage 3: label = z2 @ Wcls + bcls (60 cols)
    f32x4 acc3[4];
#pragma unroll
    for (int i = 0; i < 4; i++) acc3[i] = zero;
#pragma unroll
    for (int kt = 0; kt < 8; kt++) {
        int cb = kt * 64 + kq * 16;
        u16x8 au = *(const u16x8*)(tileB + rsel * 512 + (cb ^ ((rsel & 7) << 4)));
        bf16x8 af = __builtin_bit_cast(bf16x8, au);
        int k0 = kt * 32 + kq * 8;
#pragma unroll
        for (int nt = 0; nt < 4; nt++) {
            u16x8 bu = *(const u16x8*)(wtcls + (size_t)(nt * 16 + rsel) * 256 + k0);
            acc3[nt] = __builtin_amdgcn_mfma_f32_16x16x32_bf16(af, __builtin_bit_cast(bf16x8, bu), acc3[nt], 0, 0, 0);
        }
    }
    int rowb = wrow + kq * 4;
#pragma unroll
    for (int nt = 0; nt < 4; nt++) {
        int col = nt * 16 + rsel;
        if (col < 60) {
            float bcv = bcls[col];
#pragma unroll
            for (int r = 0; r < 4; r++)
                label[(size_t)(rowb + r) * 60 + col] = acc3[nt][r] + bcv;
        }
    }
}

// ---------------- launch ----------------
extern "C" void kernel_launch(void* const* d_in, const int* in_sizes, int n_in,
                              void* d_out, int out_size, void* d_ws, size_t ws_size,
                              hipStream_t stream) {
    const float* nf   = (const float*)d_in[0];
    const int* src    = (const int*)d_in[1];
    const int* dst    = (const int*)d_in[2];
    const int* n2g    = (const int*)d_in[3];
    const float* Wemb = (const float*)d_in[4];
    const float* bemb = (const float*)d_in[5];
    const float* Wc1  = (const float*)d_in[6];
    const float* bc1  = (const float*)d_in[7];
    const float* Wc2  = (const float*)d_in[8];
    const float* bc2  = (const float*)d_in[9];
    const float* bng  = (const float*)d_in[10];
    const float* bnb  = (const float*)d_in[11];
    const float* bnm  = (const float*)d_in[12];
    const float* bnv  = (const float*)d_in[13];
    const float* Wout = (const float*)d_in[14];
    const float* bout = (const float*)d_in[15];
    const float* Wci  = (const float*)d_in[16];
    const float* bci  = (const float*)d_in[17];
    const float* Wb3a = (const float*)d_in[18];
    const float* bb3a = (const float*)d_in[19];
    const float* Wb3b = (const float*)d_in[20];
    const float* bb3b = (const float*)d_in[21];
    const float* Wcls = (const float*)d_in[22];
    const float* bcls = (const float*)d_in[23];

    char* ws = (char*)d_ws;
    int* deg_out = (int*)(ws + OFF_DEG_OUT);
    int* deg_in  = (int*)(ws + OFF_DEG_IN);
    float* T     = (float*)(ws + OFF_T);
    float* n_out = (float*)(ws + OFF_NOUT);
    float* n_inp = (float*)(ws + OFF_NIN);
    int* row_ptr = (int*)(ws + OFF_ROWPTR);
    int* cursor  = (int*)(ws + OFF_CURSOR);
    int* csr_src = (int*)(ws + OFF_CSRS);
    int* bsum    = (int*)(ws + OFF_BSUM);
    unsigned short* wt2   = (unsigned short*)(ws + OFF_WT2);
    unsigned short* wta   = (unsigned short*)(ws + OFF_WTA);
    unsigned short* wtb   = (unsigned short*)(ws + OFF_WTB);
    unsigned short* wtcls = (unsigned short*)(ws + OFF_WTCLS);
    unsigned short* wot   = (unsigned short*)(ws + OFF_WOT);
    float* bns = (float*)(ws + OFF_BNS);
    float* bnh = (float*)(ws + OFF_BNH);
    float* TAB = (float*)(ws + OFF_TAB);
    float* PP  = (float*)(ws + OFF_PP);
    float* R3  = (float*)(ws + OFF_R3);
    unsigned short* h1w = (unsigned short*)(ws + OFF_H1W);

    float* h3d_out   = (float*)d_out;
    float* label_out = (float*)d_out + (size_t)NN * 3;

    hipMemsetAsync(ws, 0, ZERO_BYTES, stream);   // deg_out, deg_in

    k_degprep<<<EBLK + 856, 256, 0, stream>>>(src, dst, deg_out, deg_in,
                                              Wc2, Wb3a, Wb3b, wt2, wta, wtb,
                                              Wcls, wtcls, bng, bnb, bnm, bnv, bns, bnh,
                                              Wout, wot, Wemb, bemb, Wc1, bc1, bc2, TAB, PP);
    k_scan1<<<NBLK, 256, 0, stream>>>(deg_in, row_ptr, bsum);
    k_scan2<<<1, 1024, 0, stream>>>(bsum);
    k_scan3<<<NBLK, 256, 0, stream>>>(row_ptr, bsum, cursor, deg_out, deg_in, n_out, n_inp);
    k_fill<<<EBLK, 256, 0, stream>>>(src, dst, cursor, csr_src);
    k_rowstats<<<NBLK, 256, 0, stream>>>(row_ptr, csr_src, n_out, n_inp, nf, T);

    k_conv1<<<NN / 64, 256, 0, stream>>>(T, nf, TAB, n_out, wt2, wot, h1w, R3);
    k_gconv<<<NN / 64, 256, 0, stream>>>(row_ptr, csr_src, n_inp, h1w, PP, bout, R3, h3d_out);
    k_head<<<GG / 16, 64, 0, stream>>>(n2g, h3d_out, Wci, bci, wta, bb3a, wtb, bb3b,
                                       wtcls, bcls, bns, bnh, label_out);
}

// Round 15
// 220.788 us; speedup vs baseline: 2.6614x; 1.0129x over previous
//
#include <hip/hip_runtime.h>

// SimplePoseGNN on MI355X — round 15 (r14 best + scan2 folded into scan3 + gconv csr-in-LDS).
// fp32 in/out; internal bf16 + fp32 accumulation; bf16 MFMA GEMMs.
// conv1 (r10): cooperative y-build w/ scalar tables, swizzled tileY, GEMM2 + Wout
// residual tile, channel-permuted 8B stores. k_gconv (r10 + LDS csr stage).
// k_head: 64-thread blocks. Graph mean via binary search on sorted node2graph.
// k_degprep: degree atomics + ALL table prep in ONE launch (blockIdx dispatch).

#define NN 139264
#define EE 278528
#define GG 8192
#define NBLK 544    // NN/256
#define EBLK 1088   // EE/256

typedef float f32x4 __attribute__((ext_vector_type(4)));
typedef __bf16 bf16x8 __attribute__((ext_vector_type(8)));
typedef unsigned short u16x8 __attribute__((ext_vector_type(8)));
typedef unsigned short u16x4 __attribute__((ext_vector_type(4)));

__device__ __forceinline__ float bf2f(unsigned short u) {
    unsigned int i = ((unsigned int)u) << 16;
    float f;
    __builtin_memcpy(&f, &i, 4);
    return f;
}
__device__ __forceinline__ unsigned short f2bf(float f) {
    unsigned int i;
    __builtin_memcpy(&i, &f, 4);
    i += 0x7fffu + ((i >> 16) & 1u);   // round-to-nearest-even
    return (unsigned short)(i >> 16);
}
__device__ __forceinline__ unsigned short bfbits(float f) {
    __bf16 b = (__bf16)f;
    return __builtin_bit_cast(unsigned short, b);
}

// ---------------- workspace layout (bytes) ----------------
#define OFF_DEG_OUT ((size_t)0)
#define OFF_DEG_IN  ((size_t)557056)
#define ZERO_BYTES  ((size_t)1114112)
#define OFF_T       ((size_t)1114112)
#define OFF_NOUT    ((size_t)2785280)
#define OFF_NIN     ((size_t)3342336)
#define OFF_ROWPTR  ((size_t)3899392)
#define OFF_CURSOR  ((size_t)4460544)
#define OFF_CSRS    ((size_t)5017600)
#define OFF_WT2     ((size_t)6131712)
#define OFF_WTA     ((size_t)6262784)
#define OFF_WTB     ((size_t)6393856)
#define OFF_WTCLS   ((size_t)6524928)
#define OFF_WOT     ((size_t)6557696)
#define OFF_BNS     ((size_t)6565888)
#define OFF_BNH     ((size_t)6572032)
#define OFF_TAB     ((size_t)6578176)
#define OFF_PP      ((size_t)6587392)
#define OFF_BSUM    ((size_t)6595584)
#define OFF_R3      ((size_t)6599680)
#define OFF_H1W     ((size_t)8270848)
// total ~79.6 MB

// ---------------- merged degree + table prep (one launch) ----------------
__global__ void k_degprep(const int* __restrict__ src, const int* __restrict__ dst,
                          int* __restrict__ deg_out, int* __restrict__ deg_in,
                          const float* __restrict__ Wc2, const float* __restrict__ Wb3a,
                          const float* __restrict__ Wb3b,
                          unsigned short* __restrict__ wt2, unsigned short* __restrict__ wta,
                          unsigned short* __restrict__ wtb,
                          const float* __restrict__ wcls, unsigned short* __restrict__ tcls,
                          const float* __restrict__ g, const float* __restrict__ b,
                          const float* __restrict__ m, const float* __restrict__ v,
                          float* __restrict__ bns, float* __restrict__ bnh,
                          const float* __restrict__ Wout, unsigned short* __restrict__ wot,
                          const float* __restrict__ Wemb, const float* __restrict__ bemb,
                          const float* __restrict__ Wc1, const float* __restrict__ bc1,
                          const float* __restrict__ bc2,
                          float* __restrict__ TAB, float* __restrict__ PP) {
    int bid = blockIdx.x, tid = threadIdx.x;
    if (bid < EBLK) {
        int e = bid * 256 + tid;
        atomicAdd(&deg_out[src[e]], 1);
        atomicAdd(&deg_in[dst[e]], 1);
        return;
    }
    int pb = bid - EBLK;
    if (pb < 768) {
        int y = pb >> 8;
        int t = (pb & 255) * 256 + tid;
        int k = t >> 8, n = t & 255;
        const float* w = (y == 0) ? Wc2 : (y == 1) ? Wb3a : Wb3b;
        unsigned short* o = (y == 0) ? wt2 : (y == 1) ? wta : wtb;
        o[n * 256 + k] = f2bf(w[t]);
        return;
    }
    pb -= 768;
    if (pb < 64) {
        int t = pb * 256 + tid;
        int n = t >> 8, k = t & 255;
        tcls[t] = (n < 60) ? f2bf(wcls[k * 60 + n]) : (unsigned short)0;
        return;
    }
    pb -= 64;
    if (pb < 6) {
        int t = pb * 256 + tid;
        float inv = rsqrtf(v[t] + 1e-5f);
        float s = g[t] * inv;
        bns[t] = s;
        bnh[t] = b[t] - m[t] * s;
        return;
    }
    pb -= 6;
    if (pb < 16) {
        int t = pb * 256 + tid;
        int n = t >> 8, k = t & 255;
        wot[t] = (n < 3) ? f2bf(Wout[k * 3 + n]) : (unsigned short)0;
        return;
    }
    pb -= 16;
    if (pb == 0) {
        int c = tid;
        float inv0 = rsqrtf(v[c] + 1e-5f);
        float s0 = g[c] * inv0;
        float h0 = b[c] - m[c] * s0;
        float e0 = 0.f, e1 = 0.f, e2 = 0.f;
        for (int k = 0; k < 256; k++) {
            float w = Wc1[k * 256 + c];
            e0 = fmaf(Wemb[k], w, e0);
            e1 = fmaf(Wemb[256 + k], w, e1);
            e2 = fmaf(bemb[k], w, e2);
        }
        TAB[c]        = e0 * s0;
        TAB[256 + c]  = e1 * s0;
        TAB[512 + c]  = e2 * s0;
        TAB[768 + c]  = fmaf(bc1[c], s0, h0);
        float inv1 = rsqrtf(v[256 + c] + 1e-5f);
        float s1 = g[256 + c] * inv1;
        TAB[1024 + c] = s1;
        TAB[1280 + c] = b[256 + c] - m[256 + c] * s1;
        TAB[1536 + c] = Wemb[c];
        TAB[1792 + c] = Wemb[256 + c];
        TAB[2048 + c] = bemb[c];
        return;
    }
    {   // PP
        int cp = tid;
        int w = cp >> 6, rs = (cp >> 2) & 15, nt = cp & 3;
        int c = w * 64 + nt * 16 + rs;
        PP[cp] = bc2[c];
        float inv2 = rsqrtf(v[512 + c] + 1e-5f);
        float s2 = g[512 + c] * inv2;
        PP[256 + cp] = s2;
        PP[512 + cp] = b[512 + c] - m[512 + c] * s2;
        float inv3 = rsqrtf(v[768 + c] + 1e-5f);
        float s3 = g[768 + c] * inv3;
        PP[768 + cp] = s3;
        PP[1024 + cp] = b[768 + c] - m[768 + c] * s3;
        PP[1280 + cp] = Wout[c * 3];
        PP[1536 + cp] = Wout[c * 3 + 1];
        PP[1792 + cp] = Wout[c * 3 + 2];
    }
}

// ---------------- graph scans ----------------

__global__ void k_scan1(const int* __restrict__ deg, int* __restrict__ part, int* __restrict__ bsum) {
    __shared__ int sh[256];
    int t = threadIdx.x, gid = blockIdx.x * 256 + t;
    int v = deg[gid];
    sh[t] = v;
    __syncthreads();
#pragma unroll
    for (int off = 1; off < 256; off <<= 1) {
        int a = (t >= off) ? sh[t - off] : 0;
        __syncthreads();
        sh[t] += a;
        __syncthreads();
    }
    part[gid] = sh[t] - v;
    if (t == 255) bsum[blockIdx.x] = sh[t];
}

// scan3 with scan2 folded in: each block computes its own bsum prefix (L2-hot).
__global__ void k_scan3(int* __restrict__ rp, const int* __restrict__ bsum, int* __restrict__ cursor,
                        const int* __restrict__ dego, const int* __restrict__ degi,
                        float* __restrict__ n_out, float* __restrict__ n_in) {
    __shared__ int red[256];
    int t = threadIdx.x, bid = blockIdx.x;
    // prefix = sum of bsum[j] for j < bid
    int acc = 0;
#pragma unroll
    for (int k = 0; k < 3; k++) {
        int j = t + k * 256;
        if (j < bid && j < NBLK) acc += bsum[j];
    }
    red[t] = acc;
    __syncthreads();
#pragma unroll
    for (int off = 128; off; off >>= 1) {
        if (t < off) red[t] += red[t + off];
        __syncthreads();
    }
    int prefix = red[0];
    int gid = bid * 256 + t;
    int v = rp[gid] + prefix;
    rp[gid] = v;
    cursor[gid] = v;
    if (gid == 0) rp[NN] = EE;
    n_out[gid] = rsqrtf((float)max(dego[gid], 1));
    n_in[gid]  = rsqrtf((float)max(degi[gid], 1));
}

__global__ void k_fill(const int* __restrict__ src, const int* __restrict__ dst,
                       int* __restrict__ cursor, int* __restrict__ csr) {
    int e = blockIdx.x * 256 + threadIdx.x;
    int d = dst[e];
    int pos = atomicAdd(&cursor[d], 1);
    csr[pos] = src[e];
}

// per-row conv1 stats: T[r] = n_in[r] * { Σ sc*nf0, Σ sc*nf1, Σ sc },  sc = n_out[src]
__global__ void k_rowstats(const int* __restrict__ rp, const int* __restrict__ csr,
                           const float* __restrict__ n_out, const float* __restrict__ n_in,
                           const float* __restrict__ nf, float* __restrict__ T) {
    int r = blockIdx.x * 256 + threadIdx.x;
    int e0 = rp[r], e1 = rp[r + 1];
    float S0 = 0.f, S1 = 0.f, S2 = 0.f;
    for (int e = e0; e < e1; e++) {
        int s = csr[e];
        float sc = n_out[s];
        S0 = fmaf(sc, nf[2 * s], S0);
        S1 = fmaf(sc, nf[2 * s + 1], S1);
        S2 += sc;
    }
    float ni = n_in[r];
    T[3 * r]     = S0 * ni;
    T[3 * r + 1] = S1 * ni;
    T[3 * r + 2] = S2 * ni;
}

// ---------------- conv1: cooperative y-build (scalar tables) + GEMM2 + Wout tile ----
__launch_bounds__(256)
__global__ void k_conv1(const float* __restrict__ T, const float* __restrict__ nf,
                        const float* __restrict__ TAB, const float* __restrict__ n_out,
                        const unsigned short* __restrict__ Wt2, const unsigned short* __restrict__ wot,
                        unsigned short* __restrict__ h1w, float* __restrict__ R3) {
    __shared__ unsigned char tileY[64 * 512];
    int lane = threadIdx.x & 63, wave = threadIdx.x >> 6;
    int wrow = blockIdx.x * 64;
    int rsel = lane & 15, kq = lane >> 4;

    // ---- phase 1: thread (wave,lane) builds channels wave*64..+63 of row lane
    {
        int wu = __builtin_amdgcn_readfirstlane(wave);   // wave-uniform -> SGPR
        const float* tb = TAB + wu * 64;
        int row = wrow + lane;
        float t0 = T[3 * row], t1 = T[3 * row + 1], t2 = T[3 * row + 2];
        float2 p = *(const float2*)(nf + 2 * (size_t)row);
        float f0 = p.x, f1 = p.y;
        float no = n_out[row];
        int sw = (lane & 7) << 4;
        unsigned char* wb = tileY + lane * 512;
#pragma unroll
        for (int jj = 0; jj < 8; jj++) {
            int co = jj * 8;
            f32x4 ew0a = *(const f32x4*)(tb + co),        ew0b = *(const f32x4*)(tb + co + 4);
            f32x4 ew1a = *(const f32x4*)(tb + 256 + co),  ew1b = *(const f32x4*)(tb + 256 + co + 4);
            f32x4 ew2a = *(const f32x4*)(tb + 512 + co),  ew2b = *(const f32x4*)(tb + 512 + co + 4);
            f32x4 c0a  = *(const f32x4*)(tb + 768 + co),  c0b  = *(const f32x4*)(tb + 768 + co + 4);
            f32x4 s1a  = *(const f32x4*)(tb + 1024 + co), s1b  = *(const f32x4*)(tb + 1024 + co + 4);
            f32x4 h1a  = *(const f32x4*)(tb + 1280 + co), h1b  = *(const f32x4*)(tb + 1280 + co + 4);
            f32x4 w0a  = *(const f32x4*)(tb + 1536 + co), w0b  = *(const f32x4*)(tb + 1536 + co + 4);
            f32x4 w1a  = *(const f32x4*)(tb + 1792 + co), w1b  = *(const f32x4*)(tb + 1792 + co + 4);
            f32x4 bea  = *(const f32x4*)(tb + 2048 + co), beb  = *(const f32x4*)(tb + 2048 + co + 4);
            u16x8 o;
#pragma unroll
            for (int j = 0; j < 4; j++) {
                float z = fmaf(t0, ew0a[j], fmaf(t1, ew1a[j], fmaf(t2, ew2a[j], c0a[j])));
                z = fmaxf(z, 0.f);
                z = fmaxf(fmaf(z, s1a[j], h1a[j]), 0.f);
                float yv = z + fmaf(f0, w0a[j], fmaf(f1, w1a[j], bea[j]));
                o[j] = bfbits(yv * no);
            }
#pragma unroll
            for (int j = 0; j < 4; j++) {
                float z = fmaf(t0, ew0b[j], fmaf(t1, ew1b[j], fmaf(t2, ew2b[j], c0b[j])));
                z = fmaxf(z, 0.f);
                z = fmaxf(fmaf(z, s1b[j], h1b[j]), 0.f);
                float yv = z + fmaf(f0, w0b[j], fmaf(f1, w1b[j], beb[j]));
                o[4 + j] = bfbits(yv * no);
            }
            int cbyte = (wu * 64 + co) * 2;
            *(u16x8*)(wb + (cbyte ^ sw)) = o;
        }
    }
    __syncthreads();

    // ---- phase 2: GEMM2 (tileY @ W2) + Wout residual tile (wave 0)
    bool w0w = (wave == 0);
    f32x4 acc[4][4];
    f32x4 acc3[4];
    f32x4 zero = {0.f, 0.f, 0.f, 0.f};
#pragma unroll
    for (int i = 0; i < 4; i++) {
        acc3[i] = zero;
#pragma unroll
        for (int j = 0; j < 4; j++) acc[i][j] = zero;
    }
#pragma unroll
    for (int kt = 0; kt < 8; kt++) {
        int cb = kt * 64 + kq * 16;
        int k0 = kt * 32 + kq * 8;
        bf16x8 afr[4];
#pragma unroll
        for (int mt = 0; mt < 4; mt++) {
            int ar = mt * 16 + rsel;
            u16x8 au = *(const u16x8*)(tileY + ar * 512 + (cb ^ ((ar & 7) << 4)));
            afr[mt] = __builtin_bit_cast(bf16x8, au);
        }
        bf16x8 bfr[4];
#pragma unroll
        for (int nt = 0; nt < 4; nt++) {
            u16x8 bu = *(const u16x8*)(Wt2 + (size_t)(wave * 64 + nt * 16 + rsel) * 256 + k0);
            bfr[nt] = __builtin_bit_cast(bf16x8, bu);
        }
        bf16x8 bw;
        if (w0w) {
            u16x8 bu = *(const u16x8*)(wot + (size_t)rsel * 256 + k0);
            bw = __builtin_bit_cast(bf16x8, bu);
        }
#pragma unroll
        for (int mt = 0; mt < 4; mt++) {
#pragma unroll
            for (int nt = 0; nt < 4; nt++)
                acc[mt][nt] = __builtin_amdgcn_mfma_f32_16x16x32_bf16(afr[mt], bfr[nt], acc[mt][nt], 0, 0, 0);
            if (w0w)
                acc3[mt] = __builtin_amdgcn_mfma_f32_16x16x32_bf16(afr[mt], bw, acc3[mt], 0, 0, 0);
        }
    }

    // permuted coalesced stores: channel c' = wave*64 + rsel*4 + nt
#pragma unroll
    for (int mt = 0; mt < 4; mt++) {
#pragma unroll
        for (int r = 0; r < 4; r++) {
            int row = wrow + mt * 16 + kq * 4 + r;
            u16x4 o;
#pragma unroll
            for (int nt = 0; nt < 4; nt++) o[nt] = bfbits(acc[mt][nt][r]);
            *(u16x4*)(h1w + (size_t)row * 256 + wave * 64 + rsel * 4) = o;
        }
    }

    // R3 from wave 0, lanes rsel<3
    if (w0w && rsel < 3) {
#pragma unroll
        for (int mt = 0; mt < 4; mt++)
#pragma unroll
            for (int r = 0; r < 4; r++) {
                int row = wrow + mt * 16 + kq * 4 + r;
                R3[(size_t)row * 3 + rsel] = acc3[mt][r] / n_out[row];
            }
    }
}

// ---------------- k_gconv: register gather (csr staged in LDS) + permuted epilogue ----
__launch_bounds__(256)
__global__ void k_gconv(const int* __restrict__ rp, const int* __restrict__ csr,
                        const float* __restrict__ n_in, const unsigned short* __restrict__ h1w,
                        const float* __restrict__ PP, const float* __restrict__ bout,
                        const float* __restrict__ R3, float* __restrict__ h3d) {
    __shared__ int lcsr[1024];
    int hw = threadIdx.x >> 5;        // 0..7 half-waves
    int l = threadIdx.x & 31;
    int c0 = l * 8;                   // 8 permuted channels per lane

    // stage this block's contiguous csr slice into LDS (typical ~128 edges)
    int eb0 = rp[blockIdx.x * 64];
    int eb1 = rp[blockIdx.x * 64 + 64];
    int nE = eb1 - eb0;
    bool useL = (nE <= 1024);
    if (useL) {
        for (int i = threadIdx.x; i < nE; i += 256) lcsr[i] = csr[eb0 + i];
    }
    __syncthreads();

    float bc[8], s0[8], h0[8], s1[8], h1v[8], w0[8], w1[8], w2[8];
#pragma unroll
    for (int j = 0; j < 8; j += 4) {
        *(float4*)(bc + j)  = *(const float4*)(PP + c0 + j);
        *(float4*)(s0 + j)  = *(const float4*)(PP + 256 + c0 + j);
        *(float4*)(h0 + j)  = *(const float4*)(PP + 512 + c0 + j);
        *(float4*)(s1 + j)  = *(const float4*)(PP + 768 + c0 + j);
        *(float4*)(h1v + j) = *(const float4*)(PP + 1024 + c0 + j);
        *(float4*)(w0 + j)  = *(const float4*)(PP + 1280 + c0 + j);
        *(float4*)(w1 + j)  = *(const float4*)(PP + 1536 + c0 + j);
        *(float4*)(w2 + j)  = *(const float4*)(PP + 1792 + c0 + j);
    }
    float b0 = bout[0], b1 = bout[1], b2v = bout[2];

    int rbase = blockIdx.x * 64 + hw * 8;
#pragma unroll 1
    for (int i = 0; i < 8; i++) {
        int row = rbase + i;
        int e0 = rp[row], e1 = rp[row + 1];
        float a[8] = {0.f, 0.f, 0.f, 0.f, 0.f, 0.f, 0.f, 0.f};
        if (useL) {
            for (int e = e0; e < e1; e++) {
                int s = lcsr[e - eb0];
                u16x8 v = *(const u16x8*)(h1w + ((size_t)s << 8) + c0);
#pragma unroll
                for (int j = 0; j < 8; j++) a[j] += bf2f(v[j]);
            }
        } else {
            for (int e = e0; e < e1; e++) {
                int s = csr[e];
                u16x8 v = *(const u16x8*)(h1w + ((size_t)s << 8) + c0);
#pragma unroll
                for (int j = 0; j < 8; j++) a[j] += bf2f(v[j]);
            }
        }
        float ni = n_in[row];
        float p0 = 0.f, p1 = 0.f, p2 = 0.f;
#pragma unroll
        for (int j = 0; j < 8; j++) {
            float y = fmaf(a[j], ni, bc[j]);
            y = fmaxf(fmaf(y, s0[j], h0[j]), 0.f);
            y = fmaxf(fmaf(y, s1[j], h1v[j]), 0.f);
            p0 = fmaf(y, w0[j], p0);
            p1 = fmaf(y, w1[j], p1);
            p2 = fmaf(y, w2[j], p2);
        }
#pragma unroll
        for (int m = 1; m < 32; m <<= 1) {
            p0 += __shfl_xor(p0, m, 32);
            p1 += __shfl_xor(p1, m, 32);
            p2 += __shfl_xor(p2, m, 32);
        }
        if (l == 0) {
            size_t o = (size_t)row * 3;
            h3d[o]     = p0 + R3[o]     + b0;
            h3d[o + 1] = p1 + R3[o + 1] + b1;
            h3d[o + 2] = p2 + R3[o + 2] + b2v;
        }
    }
}

// ---------------- fused classification head: 1 wave per block, 16 graphs ----------
__launch_bounds__(64)
__global__ void k_head(const int* __restrict__ n2g, const float* __restrict__ h3d,
                       const float* __restrict__ Wci, const float* __restrict__ bci,
                       const unsigned short* __restrict__ wta, const float* __restrict__ ba,
                       const unsigned short* __restrict__ wtb, const float* __restrict__ bb,
                       const unsigned short* __restrict__ wtcls, const float* __restrict__ bcls,
                       const float* __restrict__ bns, const float* __restrict__ bnh,
                       float* __restrict__ label) {
    __shared__ unsigned char tileA[8192];
    __shared__ unsigned char tileB[8192];
    int lane = threadIdx.x;
    int wrow = blockIdx.x * 16;
    int rsel = lane & 15, kq = lane >> 4;
    int g = wrow + rsel;

    int lo = 0, hi = NN;
    while (lo < hi) { int mid = (lo + hi) >> 1; if (n2g[mid] < g) lo = mid + 1; else hi = mid; }
    int s = lo;
    hi = NN;
    while (lo < hi) { int mid = (lo + hi) >> 1; if (n2g[mid] < g + 1) lo = mid + 1; else hi = mid; }
    int e = lo;
    float m0 = 0.f, m1 = 0.f, m2 = 0.f;
    for (int j = s; j < e; j++) {
        m0 += h3d[(size_t)j * 3];
        m1 += h3d[(size_t)j * 3 + 1];
        m2 += h3d[(size_t)j * 3 + 2];
    }
    float inv = 1.f / fmaxf((float)(e - s), 1.f);
    m0 *= inv; m1 *= inv; m2 *= inv;

    f32x4 zero = {0.f, 0.f, 0.f, 0.f};
    f32x4 acc[16];
#pragma unroll
    for (int i = 0; i < 16; i++) acc[i] = zero;

    // stage 1: z1 = relu(bn4(z0 @ Wa + ba)), z0 built on the fly
#pragma unroll
    for (int kt = 0; kt < 8; kt++) {
        int k0 = kt * 32 + kq * 8;
        u16x8 au;
#pragma unroll
        for (int j = 0; j < 8; j++)
            au[j] = f2bf(fmaf(m0, Wci[k0 + j], fmaf(m1, Wci[256 + k0 + j],
                         fmaf(m2, Wci[512 + k0 + j], bci[k0 + j]))));
        bf16x8 af = __builtin_bit_cast(bf16x8, au);
#pragma unroll
        for (int nt = 0; nt < 16; nt++) {
            u16x8 bu = *(const u16x8*)(wta + (size_t)(nt * 16 + rsel) * 256 + k0);
            acc[nt] = __builtin_amdgcn_mfma_f32_16x16x32_bf16(af, __builtin_bit_cast(bf16x8, bu), acc[nt], 0, 0, 0);
        }
    }
#pragma unroll
    for (int nt = 0; nt < 16; nt++) {
        int col = nt * 16 + rsel;
        float bcv = ba[col];
        float sc = bns[4 * 256 + col], h = bnh[4 * 256 + col];
#pragma unroll
        for (int r = 0; r < 4; r++) {
            float y = fmaxf(fmaf(acc[nt][r] + bcv, sc, h), 0.f);
            int rr = kq * 4 + r;
            *(unsigned short*)(tileA + rr * 512 + ((col * 2) ^ ((rr & 7) << 4))) = f2bf(y);
        }
    }

    // stage 2: z2 = relu(bn5(z1 @ Wb + bb))
#pragma unroll
    for (int i = 0; i < 16; i++) acc[i] = zero;
#pragma unroll
    for (int kt = 0; kt < 8; kt++) {
        int cb = kt * 64 + kq * 16;
        u16x8 au = *(const u16x8*)(tileA + rsel * 512 + (cb ^ ((rsel & 7) << 4)));
        bf16x8 af = __builtin_bit_cast(bf16x8, au);
        int k0 = kt * 32 + kq * 8;
#pragma unroll
        for (int nt = 0; nt < 16; nt++) {
            u16x8 bu = *(const u16x8*)(wtb + (size_t)(nt * 16 + rsel) * 256 + k0);
            acc[nt] = __builtin_amdgcn_mfma_f32_16x16x32_bf16(af, __builtin_bit_cast(bf16x8, bu), acc[nt], 0, 0, 0);
        }
    }
#pragma unroll
    for (int nt = 0; nt < 16; nt++) {
        int col = nt * 16 + rsel;
        float bcv = bb[col];
        float sc = bns[5 * 256 + col], h = bnh[5 * 256 + col];
#pragma unroll
        for (int r = 0; r < 4; r++) {
            float y = fmaxf(fmaf(acc[nt][r] + bcv, sc, h), 0.f);
            int rr = kq * 4 + r;
            *(unsigned short*)(tileB + rr * 512 + ((col * 2) ^ ((rr & 7) << 4))) = f2bf(y);
        }
    }

    // stage 3: label = z2 @ Wcls + bcls (60 cols)
    f32x4 acc3[4];
#pragma unroll
    for (int i = 0; i < 4; i++) acc3[i] = zero;
#pragma unroll
    for (int kt = 0; kt < 8; kt++) {
        int cb = kt * 64 + kq * 16;
        u16x8 au = *(const u16x8*)(tileB + rsel * 512 + (cb ^ ((rsel & 7) << 4)));
        bf16x8 af = __builtin_bit_cast(bf16x8, au);
        int k0 = kt * 32 + kq * 8;
#pragma unroll
        for (int nt = 0; nt < 4; nt++) {
            u16x8 bu = *(const u16x8*)(wtcls + (size_t)(nt * 16 + rsel) * 256 + k0);
            acc3[nt] = __builtin_amdgcn_mfma_f32_16x16x32_bf16(af, __builtin_bit_cast(bf16x8, bu), acc3[nt], 0, 0, 0);
        }
    }
    int rowb = wrow + kq * 4;
#pragma unroll
    for (int nt = 0; nt < 4; nt++) {
        int col = nt * 16 + rsel;
        if (col < 60) {
            float bcv = bcls[col];
#pragma unroll
            for (int r = 0; r < 4; r++)
                label[(size_t)(rowb + r) * 60 + col] = acc3[nt][r] + bcv;
        }
    }
}

// ---------------- launch ----------------
extern "C" void kernel_launch(void* const* d_in, const int* in_sizes, int n_in,
                              void* d_out, int out_size, void* d_ws, size_t ws_size,
                              hipStream_t stream) {
    const float* nf   = (const float*)d_in[0];
    const int* src    = (const int*)d_in[1];
    const int* dst    = (const int*)d_in[2];
    const int* n2g    = (const int*)d_in[3];
    const float* Wemb = (const float*)d_in[4];
    const float* bemb = (const float*)d_in[5];
    const float* Wc1  = (const float*)d_in[6];
    const float* bc1  = (const float*)d_in[7];
    const float* Wc2  = (const float*)d_in[8];
    const float* bc2  = (const float*)d_in[9];
    const float* bng  = (const float*)d_in[10];
    const float* bnb  = (const float*)d_in[11];
    const float* bnm  = (const float*)d_in[12];
    const float* bnv  = (const float*)d_in[13];
    const float* Wout = (const float*)d_in[14];
    const float* bout = (const float*)d_in[15];
    const float* Wci  = (const float*)d_in[16];
    const float* bci  = (const float*)d_in[17];
    const float* Wb3a = (const float*)d_in[18];
    const float* bb3a = (const float*)d_in[19];
    const float* Wb3b = (const float*)d_in[20];
    const float* bb3b = (const float*)d_in[21];
    const float* Wcls = (const float*)d_in[22];
    const float* bcls = (const float*)d_in[23];

    char* ws = (char*)d_ws;
    int* deg_out = (int*)(ws + OFF_DEG_OUT);
    int* deg_in  = (int*)(ws + OFF_DEG_IN);
    float* T     = (float*)(ws + OFF_T);
    float* n_out = (float*)(ws + OFF_NOUT);
    float* n_inp = (float*)(ws + OFF_NIN);
    int* row_ptr = (int*)(ws + OFF_ROWPTR);
    int* cursor  = (int*)(ws + OFF_CURSOR);
    int* csr_src = (int*)(ws + OFF_CSRS);
    int* bsum    = (int*)(ws + OFF_BSUM);
    unsigned short* wt2   = (unsigned short*)(ws + OFF_WT2);
    unsigned short* wta   = (unsigned short*)(ws + OFF_WTA);
    unsigned short* wtb   = (unsigned short*)(ws + OFF_WTB);
    unsigned short* wtcls = (unsigned short*)(ws + OFF_WTCLS);
    unsigned short* wot   = (unsigned short*)(ws + OFF_WOT);
    float* bns = (float*)(ws + OFF_BNS);
    float* bnh = (float*)(ws + OFF_BNH);
    float* TAB = (float*)(ws + OFF_TAB);
    float* PP  = (float*)(ws + OFF_PP);
    float* R3  = (float*)(ws + OFF_R3);
    unsigned short* h1w = (unsigned short*)(ws + OFF_H1W);

    float* h3d_out   = (float*)d_out;
    float* label_out = (float*)d_out + (size_t)NN * 3;

    hipMemsetAsync(ws, 0, ZERO_BYTES, stream);   // deg_out, deg_in

    k_degprep<<<EBLK + 856, 256, 0, stream>>>(src, dst, deg_out, deg_in,
                                              Wc2, Wb3a, Wb3b, wt2, wta, wtb,
                                              Wcls, wtcls, bng, bnb, bnm, bnv, bns, bnh,
                                              Wout, wot, Wemb, bemb, Wc1, bc1, bc2, TAB, PP);
    k_scan1<<<NBLK, 256, 0, stream>>>(deg_in, row_ptr, bsum);
    k_scan3<<<NBLK, 256, 0, stream>>>(row_ptr, bsum, cursor, deg_out, deg_in, n_out, n_inp);
    k_fill<<<EBLK, 256, 0, stream>>>(src, dst, cursor, csr_src);
    k_rowstats<<<NBLK, 256, 0, stream>>>(row_ptr, csr_src, n_out, n_inp, nf, T);

    k_conv1<<<NN / 64, 256, 0, stream>>>(T, nf, TAB, n_out, wt2, wot, h1w, R3);
    k_gconv<<<NN / 64, 256, 0, stream>>>(row_ptr, csr_src, n_inp, h1w, PP, bout, R3, h3d_out);
    k_head<<<GG / 16, 64, 0, stream>>>(n2g, h3d_out, Wci, bci, wta, bb3a, wtb, bb3b,
                                       wtcls, bcls, bns, bnh, label_out);
}